// Round 1
// 674.424 us; speedup vs baseline: 1.1190x; 1.1190x over previous
//
#include <hip/hip_runtime.h>

// GraphSAGE 2-layer encoder, MI355X (gfx950).  Round 3.
// vs R2: parallel 3-kernel CSR scan (was 1-block strided scan), agg kernels
// rebuilt as 16B/lane paired-edge gathers (2x outstanding bytes), XCD-chunk
// swizzle on both GEMMs (A-panel L2 reuse), misc+cvt fused, cursor memset
// eliminated (scan writes cursor=off directly).
//   GEMM1: Cl = x@w1_l^T ; Cr = x@w1_r^T + b1          (bf16, [Mpad,256] each)
//   agg1 : h[n] = relu(mean(Cl[src]) + Cr[n])          (bf16 [Mpad,256])
//   agg2 : mean2[n] = mean(h[src])                     (bf16 [Mpad,256])
//   GEMM2: out = [mean2|h] @ [w2_l|w2_r]^T + b2        (fp32 [nN,512])

#define IN_DIM  1024
#define HID_DIM 256
#define OUT_N   512

typedef __attribute__((ext_vector_type(8))) short bf16x8;
typedef __attribute__((ext_vector_type(4))) float f32x4;

static __device__ __forceinline__ unsigned short f2bf(float f) {
  unsigned int u = __float_as_uint(f);
  u += 0x7fffu + ((u >> 16) & 1u);
  return (unsigned short)(u >> 16);
}
static __device__ __forceinline__ float bf2f(unsigned short b) {
  return __uint_as_float(((unsigned int)b) << 16);
}

static __device__ __forceinline__ int load_idx(const void* ei, long long pos, int is64) {
  if (is64) return (int)((const long long*)ei)[pos];
  return ((const int*)ei)[pos];
}

// ---------- fused: edge-dtype detect + weight conversions + x->bf16 ----------
// block 0: detect; [1,513): w1cat; [513,769): w2cat; [769,...): cvt x
__global__ void k_pre(const unsigned int* __restrict__ ei, int* __restrict__ flag,
                      const float* __restrict__ w1l, const float* __restrict__ w1r,
                      unsigned short* __restrict__ W1c,
                      const float* __restrict__ w2l, const float* __restrict__ w2r,
                      unsigned short* __restrict__ W2c,
                      const float* __restrict__ x, unsigned short* __restrict__ xbf,
                      int n4) {
  int b = blockIdx.x;
  if (b == 0) {
    if (threadIdx.x < 64) {
      unsigned int v = ei[2 * threadIdx.x + 1];
      unsigned long long m = __ballot(v == 0u);
      if (threadIdx.x == 0) *flag = (m == ~0ull) ? 1 : 0;
    }
    return;
  }
  if (b < 513) {                      // W1cat[n][k], n<256 -> w1_l else w1_r; K=1024
    int i = (b - 1) * 256 + threadIdx.x;
    int base = i * 4;
    int n = base / IN_DIM, k = base % IN_DIM;
    const float* s = (n < HID_DIM) ? &w1l[(size_t)n * IN_DIM + k]
                                   : &w1r[(size_t)(n - HID_DIM) * IN_DIM + k];
    float4 v = *(const float4*)s;
    ushort4 o = { f2bf(v.x), f2bf(v.y), f2bf(v.z), f2bf(v.w) };
    *(ushort4*)&W1c[base] = o;
    return;
  }
  if (b < 769) {                      // W2cat[n][k], k<256 -> w2_l else w2_r; K=512
    int i = (b - 513) * 256 + threadIdx.x;
    int base = i * 4;
    int n = base >> 9, k = base & 511;
    const float* s = (k < HID_DIM) ? &w2l[(size_t)n * HID_DIM + k]
                                   : &w2r[(size_t)n * HID_DIM + (k - HID_DIM)];
    float4 v = *(const float4*)s;
    ushort4 o = { f2bf(v.x), f2bf(v.y), f2bf(v.z), f2bf(v.w) };
    *(ushort4*)&W2c[base] = o;
    return;
  }
  int i = (b - 769) * 256 + threadIdx.x;
  if (i >= n4) return;
  float4 v = ((const float4*)x)[i];
  ushort4 o = { f2bf(v.x), f2bf(v.y), f2bf(v.z), f2bf(v.w) };
  ((ushort4*)xbf)[i] = o;
}

// ---------- CSR build ----------
__global__ void k_deg(const void* ei, int nE, const int* flag, int* deg) {
  int e = blockIdx.x * 256 + threadIdx.x;
  if (e >= nE) return;
  int d = load_idx(ei, (long long)nE + e, *flag);
  atomicAdd(&deg[d], 1);
}

// block b sums deg[b*1024 .. b*1024+1024) -> bsum[b]   (deg zero-padded to 1024)
__global__ void k_bsum(const int* __restrict__ deg, int* __restrict__ bsum) {
  int t = threadIdx.x;
  int4 d4 = ((const int4*)(deg + (size_t)blockIdx.x * 1024))[t];
  int v = d4.x + d4.y + d4.z + d4.w;
#pragma unroll
  for (int d = 1; d < 64; d <<= 1) v += __shfl_xor(v, d);
  __shared__ int ws[4];
  if ((t & 63) == 0) ws[t >> 6] = v;
  __syncthreads();
  if (t == 0) bsum[blockIdx.x] = ws[0] + ws[1] + ws[2] + ws[3];
}

// inclusive scan of bsum[0..nb), nb <= 1024
__global__ __launch_bounds__(1024) void k_bscan(int* __restrict__ bsum, int nb) {
  __shared__ int s[1024];
  int t = threadIdx.x;
  s[t] = (t < nb) ? bsum[t] : 0;
  __syncthreads();
  for (int d = 1; d < 1024; d <<= 1) {
    int v = (t >= d) ? s[t - d] : 0;
    __syncthreads();
    s[t] += v;
    __syncthreads();
  }
  if (t < nb) bsum[t] = s[t];
}

// block b: exclusive scan of its 1024 degs + block prefix -> off[] and cursor[]
__global__ __launch_bounds__(256) void k_offsets(const int* __restrict__ deg,
                                                 const int* __restrict__ bsumInc,
                                                 int* __restrict__ off,
                                                 int* __restrict__ cursor) {
  const int t = threadIdx.x;
  const int l = t & 63, w = t >> 6;
  const size_t base = (size_t)blockIdx.x * 1024;
  int4 d4 = ((const int4*)(deg + base))[t];
  int tsum = d4.x + d4.y + d4.z + d4.w;
  int incl = tsum;
#pragma unroll
  for (int d = 1; d < 64; d <<= 1) {
    int u = __shfl_up(incl, d);
    if (l >= d) incl += u;
  }
  __shared__ int wt[4];
  if (l == 63) wt[w] = incl;
  __syncthreads();
  int wpre = 0;
  for (int i = 0; i < w; ++i) wpre += wt[i];
  int bpre = (blockIdx.x == 0) ? 0 : bsumInc[blockIdx.x - 1];
  int excl = bpre + wpre + incl - tsum;
  int4 o;
  o.x = excl;
  o.y = excl + d4.x;
  o.z = o.y + d4.y;
  o.w = o.z + d4.z;
  ((int4*)(off + base))[t] = o;
  ((int4*)(cursor + base))[t] = o;
}

__global__ void k_fill(const void* ei, int nE, const int* flag,
                       int* cursor, int* __restrict__ csr) {
  int e = blockIdx.x * 256 + threadIdx.x;
  if (e >= nE) return;
  int is64 = *flag;
  int s = load_idx(ei, e, is64);
  int d = load_idx(ei, (long long)nE + e, is64);
  int p = atomicAdd(&cursor[d], 1);
  csr[p] = s;
}

// ---------- GEMMs (m97-style: 128x128 tile, BK=32, 4 waves 2x2, 4x4 mfma) ----------
static __device__ __forceinline__ void load_lds16(const void* g, void* lds) {
  __builtin_amdgcn_global_load_lds(
      (const __attribute__((address_space(1))) unsigned int*)g,
      (__attribute__((address_space(3))) unsigned int*)lds, 16, 0, 0);
}

// bijective XCD-chunk swizzle (m204): consecutive logical tiles land on one XCD
static __device__ __forceinline__ int xcd_swz(int orig, int nwg) {
  const int q = nwg >> 3, r = nwg & 7;
  const int xcd = orig & 7, rk = orig >> 3;
  return (xcd < r) ? xcd * (q + 1) + rk : r * (q + 1) + (xcd - r) * q + rk;
}

// GEMM1: A=[Mpad,1024] bf16, B=W1c[512,1024] bf16; out split Cl/Cr (+b1 on right)
__global__ __launch_bounds__(256) void k_gemm1(const unsigned short* __restrict__ A,
                                               const unsigned short* __restrict__ B,
                                               unsigned short* __restrict__ Cl,
                                               unsigned short* __restrict__ Cr,
                                               const float* __restrict__ b1) {
  __shared__ unsigned short As[128 * 32];
  __shared__ unsigned short Bs[128 * 32];
  const int tid = threadIdx.x;
  const int w = tid >> 6, l = tid & 63;
  const int wm = w >> 1, wn = w & 1;
  const int quad = l >> 4, lane16 = l & 15;
  const int nwg = gridDim.x * gridDim.y;
  const int wg = xcd_swz(blockIdx.y * gridDim.x + blockIdx.x, nwg);
  const int m0 = (wg / gridDim.x) * 128;
  const int n0 = (wg % gridDim.x) * 128;

  f32x4 acc[4][4] = {};
  for (int k0 = 0; k0 < IN_DIM; k0 += 32) {
#pragma unroll
    for (int c = 0; c < 2; ++c) {
      const int flat = ((w * 2 + c) << 10);
      const int fb = flat + l * 16;
      const int row = fb >> 6;
      const int cb = fb & 63;
      load_lds16(A + (size_t)(m0 + row) * IN_DIM + (k0 + (cb >> 1)), (char*)As + flat);
      load_lds16(B + (size_t)(n0 + row) * IN_DIM + (k0 + (cb >> 1)), (char*)Bs + flat);
    }
    __syncthreads();
    bf16x8 af[4], bfr[4];
#pragma unroll
    for (int i = 0; i < 4; ++i)
      af[i] = *(const bf16x8*)&As[(wm * 64 + i * 16 + lane16) * 32 + quad * 8];
#pragma unroll
    for (int j = 0; j < 4; ++j)
      bfr[j] = *(const bf16x8*)&Bs[(wn * 64 + j * 16 + lane16) * 32 + quad * 8];
#pragma unroll
    for (int i = 0; i < 4; ++i)
#pragma unroll
      for (int j = 0; j < 4; ++j)
        acc[i][j] = __builtin_amdgcn_mfma_f32_16x16x32_bf16(af[i], bfr[j], acc[i][j], 0, 0, 0);
    __syncthreads();
  }

  const bool right = (n0 >= 256);
  unsigned short* Cb = right ? Cr : Cl;
  const int nc0 = n0 - (right ? 256 : 0);
#pragma unroll
  for (int i = 0; i < 4; ++i) {
    const int rbase = m0 + wm * 64 + i * 16 + quad * 4;
#pragma unroll
    for (int j = 0; j < 4; ++j) {
      const int col = nc0 + wn * 64 + j * 16 + lane16;
      const float bv = right ? b1[col] : 0.0f;
#pragma unroll
      for (int r = 0; r < 4; ++r)
        Cb[(size_t)(rbase + r) * HID_DIM + col] = f2bf(acc[i][j][r] + bv);
    }
  }
}

// GEMM2: A k<256 from Am (mean2), k>=256 from Ah (h); B=W2c[512,512]; fp32 out + b2
__global__ __launch_bounds__(256) void k_gemm2(const unsigned short* __restrict__ Am,
                                               const unsigned short* __restrict__ Ah,
                                               const unsigned short* __restrict__ B,
                                               float* __restrict__ out,
                                               const float* __restrict__ b2, int Mstore) {
  __shared__ unsigned short As[128 * 32];
  __shared__ unsigned short Bs[128 * 32];
  const int tid = threadIdx.x;
  const int w = tid >> 6, l = tid & 63;
  const int wm = w >> 1, wn = w & 1;
  const int quad = l >> 4, lane16 = l & 15;
  const int nwg = gridDim.x * gridDim.y;
  const int wg = xcd_swz(blockIdx.y * gridDim.x + blockIdx.x, nwg);
  const int m0 = (wg / gridDim.x) * 128;
  const int n0 = (wg % gridDim.x) * 128;

  f32x4 acc[4][4] = {};
  for (int k0 = 0; k0 < 2 * HID_DIM; k0 += 32) {
    const unsigned short* Abase = (k0 < HID_DIM) ? Am + k0 : Ah + (k0 - HID_DIM);
#pragma unroll
    for (int c = 0; c < 2; ++c) {
      const int flat = ((w * 2 + c) << 10);
      const int fb = flat + l * 16;
      const int row = fb >> 6;
      const int cb = fb & 63;
      load_lds16(Abase + (size_t)(m0 + row) * HID_DIM + (cb >> 1), (char*)As + flat);
      load_lds16(B + (size_t)(n0 + row) * (2 * HID_DIM) + (k0 + (cb >> 1)), (char*)Bs + flat);
    }
    __syncthreads();
    bf16x8 af[4], bfr[4];
#pragma unroll
    for (int i = 0; i < 4; ++i)
      af[i] = *(const bf16x8*)&As[(wm * 64 + i * 16 + lane16) * 32 + quad * 8];
#pragma unroll
    for (int j = 0; j < 4; ++j)
      bfr[j] = *(const bf16x8*)&Bs[(wn * 64 + j * 16 + lane16) * 32 + quad * 8];
#pragma unroll
    for (int i = 0; i < 4; ++i)
#pragma unroll
      for (int j = 0; j < 4; ++j)
        acc[i][j] = __builtin_amdgcn_mfma_f32_16x16x32_bf16(af[i], bfr[j], acc[i][j], 0, 0, 0);
    __syncthreads();
  }

#pragma unroll
  for (int i = 0; i < 4; ++i) {
    const int rbase = m0 + wm * 64 + i * 16 + quad * 4;
#pragma unroll
    for (int j = 0; j < 4; ++j) {
      const int col = n0 + wn * 64 + j * 16 + lane16;
      const float bv = b2[col];
#pragma unroll
      for (int r = 0; r < 4; ++r) {
        const int rowi = rbase + r;
        if (rowi < Mstore) out[(size_t)rowi * OUT_N + col] = acc[i][j][r] + bv;
      }
    }
  }
}

// ---------- aggregations: 1 wave/node, 16B/lane (32 lanes/row), paired edges ----------
// half h (lanes h*32..) processes edges s+2k+h; 4 pairs batched -> 8 rows in flight.
#define ACC8(v) { a0 += bf2f((unsigned short)(v)[0]); a1 += bf2f((unsigned short)(v)[1]); \
                  a2 += bf2f((unsigned short)(v)[2]); a3 += bf2f((unsigned short)(v)[3]); \
                  a4 += bf2f((unsigned short)(v)[4]); a5 += bf2f((unsigned short)(v)[5]); \
                  a6 += bf2f((unsigned short)(v)[6]); a7 += bf2f((unsigned short)(v)[7]); }

__global__ void k_agg1(const unsigned short* __restrict__ Cl,
                       const unsigned short* __restrict__ Cr,
                       const int* __restrict__ off, const int* __restrict__ csr,
                       unsigned short* __restrict__ h, int nNodes) {
  int node = blockIdx.x * 4 + (threadIdx.x >> 6);
  if (node >= nNodes) return;
  const int l = threadIdx.x & 63;
  const int half = l >> 5, li = l & 31;
  const size_t colb = (size_t)li * 8;
  int s = off[node], e = off[node + 1];
  int cnt = e - s;
  int P = cnt >> 1;
  float a0 = 0.f, a1 = 0.f, a2 = 0.f, a3 = 0.f, a4 = 0.f, a5 = 0.f, a6 = 0.f, a7 = 0.f;
  int k = 0;
  for (; k + 4 <= P; k += 4) {
    int ib = s + 2 * k + half;
    int s0 = csr[ib], s1 = csr[ib + 2], s2 = csr[ib + 4], s3 = csr[ib + 6];
    bf16x8 v0 = *(const bf16x8*)&Cl[(size_t)s0 * HID_DIM + colb];
    bf16x8 v1 = *(const bf16x8*)&Cl[(size_t)s1 * HID_DIM + colb];
    bf16x8 v2 = *(const bf16x8*)&Cl[(size_t)s2 * HID_DIM + colb];
    bf16x8 v3 = *(const bf16x8*)&Cl[(size_t)s3 * HID_DIM + colb];
    ACC8(v0); ACC8(v1); ACC8(v2); ACC8(v3);
  }
  for (; k < P; ++k) {
    int ib = s + 2 * k + half;
    bf16x8 v = *(const bf16x8*)&Cl[(size_t)csr[ib] * HID_DIM + colb];
    ACC8(v);
  }
  if ((cnt & 1) && half == 0) {
    bf16x8 v = *(const bf16x8*)&Cl[(size_t)csr[e - 1] * HID_DIM + colb];
    ACC8(v);
  }
  a0 += __shfl_xor(a0, 32); a1 += __shfl_xor(a1, 32);
  a2 += __shfl_xor(a2, 32); a3 += __shfl_xor(a3, 32);
  a4 += __shfl_xor(a4, 32); a5 += __shfl_xor(a5, 32);
  a6 += __shfl_xor(a6, 32); a7 += __shfl_xor(a7, 32);
  if (half == 0) {
    float inv = 1.0f / fmaxf((float)cnt, 1.0f);
    bf16x8 xr = *(const bf16x8*)&Cr[(size_t)node * HID_DIM + colb];   // includes b1
    bf16x8 o;
    o[0] = (short)f2bf(fmaxf(a0 * inv + bf2f((unsigned short)xr[0]), 0.0f));
    o[1] = (short)f2bf(fmaxf(a1 * inv + bf2f((unsigned short)xr[1]), 0.0f));
    o[2] = (short)f2bf(fmaxf(a2 * inv + bf2f((unsigned short)xr[2]), 0.0f));
    o[3] = (short)f2bf(fmaxf(a3 * inv + bf2f((unsigned short)xr[3]), 0.0f));
    o[4] = (short)f2bf(fmaxf(a4 * inv + bf2f((unsigned short)xr[4]), 0.0f));
    o[5] = (short)f2bf(fmaxf(a5 * inv + bf2f((unsigned short)xr[5]), 0.0f));
    o[6] = (short)f2bf(fmaxf(a6 * inv + bf2f((unsigned short)xr[6]), 0.0f));
    o[7] = (short)f2bf(fmaxf(a7 * inv + bf2f((unsigned short)xr[7]), 0.0f));
    *(bf16x8*)&h[(size_t)node * HID_DIM + colb] = o;
  }
}

__global__ void k_agg2(const unsigned short* __restrict__ hsrc,
                       const int* __restrict__ off, const int* __restrict__ csr,
                       unsigned short* __restrict__ mean2, int nNodes) {
  int node = blockIdx.x * 4 + (threadIdx.x >> 6);
  if (node >= nNodes) return;
  const int l = threadIdx.x & 63;
  const int half = l >> 5, li = l & 31;
  const size_t colb = (size_t)li * 8;
  int s = off[node], e = off[node + 1];
  int cnt = e - s;
  int P = cnt >> 1;
  float a0 = 0.f, a1 = 0.f, a2 = 0.f, a3 = 0.f, a4 = 0.f, a5 = 0.f, a6 = 0.f, a7 = 0.f;
  int k = 0;
  for (; k + 4 <= P; k += 4) {
    int ib = s + 2 * k + half;
    int s0 = csr[ib], s1 = csr[ib + 2], s2 = csr[ib + 4], s3 = csr[ib + 6];
    bf16x8 v0 = *(const bf16x8*)&hsrc[(size_t)s0 * HID_DIM + colb];
    bf16x8 v1 = *(const bf16x8*)&hsrc[(size_t)s1 * HID_DIM + colb];
    bf16x8 v2 = *(const bf16x8*)&hsrc[(size_t)s2 * HID_DIM + colb];
    bf16x8 v3 = *(const bf16x8*)&hsrc[(size_t)s3 * HID_DIM + colb];
    ACC8(v0); ACC8(v1); ACC8(v2); ACC8(v3);
  }
  for (; k < P; ++k) {
    int ib = s + 2 * k + half;
    bf16x8 v = *(const bf16x8*)&hsrc[(size_t)csr[ib] * HID_DIM + colb];
    ACC8(v);
  }
  if ((cnt & 1) && half == 0) {
    bf16x8 v = *(const bf16x8*)&hsrc[(size_t)csr[e - 1] * HID_DIM + colb];
    ACC8(v);
  }
  a0 += __shfl_xor(a0, 32); a1 += __shfl_xor(a1, 32);
  a2 += __shfl_xor(a2, 32); a3 += __shfl_xor(a3, 32);
  a4 += __shfl_xor(a4, 32); a5 += __shfl_xor(a5, 32);
  a6 += __shfl_xor(a6, 32); a7 += __shfl_xor(a7, 32);
  if (half == 0) {
    float inv = 1.0f / fmaxf((float)cnt, 1.0f);
    bf16x8 o;
    o[0] = (short)f2bf(a0 * inv); o[1] = (short)f2bf(a1 * inv);
    o[2] = (short)f2bf(a2 * inv); o[3] = (short)f2bf(a3 * inv);
    o[4] = (short)f2bf(a4 * inv); o[5] = (short)f2bf(a5 * inv);
    o[6] = (short)f2bf(a6 * inv); o[7] = (short)f2bf(a7 * inv);
    *(bf16x8*)&mean2[(size_t)node * HID_DIM + colb] = o;
  }
}

extern "C" void kernel_launch(void* const* d_in, const int* in_sizes, int n_in,
                              void* d_out, int out_size, void* d_ws, size_t ws_size,
                              hipStream_t stream) {
  const float* x   = (const float*)d_in[0];
  const void*  ei  = d_in[1];
  const float* w1l = (const float*)d_in[2];
  const float* w1r = (const float*)d_in[3];
  const float* b1  = (const float*)d_in[4];
  const float* w2l = (const float*)d_in[5];
  const float* w2r = (const float*)d_in[6];
  const float* b2  = (const float*)d_in[7];
  float* out = (float*)d_out;

  const int nN   = in_sizes[0] / IN_DIM;         // 50000
  const int nE   = in_sizes[1] / 2;              // 800000
  const int Mpad = (nN + 127) & ~127;            // 50048
  const int padN = (nN + 1023) & ~1023;          // 50176 (scan granularity)
  const int nb   = padN >> 10;                   // 49 scan blocks

  char* ws = (char*)d_ws;
  size_t o = 0;
  auto alloc = [&](size_t bytes) {
    char* p = ws + o;
    o += (bytes + 255) & ~(size_t)255;
    return p;
  };
  unsigned short* xbf   = (unsigned short*)alloc((size_t)Mpad * IN_DIM * 2);
  unsigned short* W1c   = (unsigned short*)alloc((size_t)2 * HID_DIM * IN_DIM * 2);
  unsigned short* W2c   = (unsigned short*)alloc((size_t)OUT_N * 2 * HID_DIM * 2);
  unsigned short* Cl    = (unsigned short*)alloc((size_t)Mpad * HID_DIM * 2);
  unsigned short* Cr    = (unsigned short*)alloc((size_t)Mpad * HID_DIM * 2);
  unsigned short* hbuf  = (unsigned short*)alloc((size_t)Mpad * HID_DIM * 2);
  unsigned short* mean2 = (unsigned short*)alloc((size_t)Mpad * HID_DIM * 2);
  int* deg    = (int*)alloc((size_t)padN * 4);         // zero-padded for int4 scan
  int* offs   = (int*)alloc((size_t)padN * 4);         // off[nN]=nE lands in pad region
  int* cursor = (int*)alloc((size_t)padN * 4);
  int* bsum   = (int*)alloc((size_t)1024 * 4);
  int* csr    = (int*)alloc((size_t)nE * 4);
  int* flag   = (int*)alloc(256);

  hipMemsetAsync(deg, 0, (size_t)padN * 4, stream);
  // pad rows of xbf / hbuf / mean2 stay 0xAA poison: decodes to ~1e-13 bf16,
  // flows only into pad rows of Cl/Cr/out-guarded stores -> never observed.

  const int n4 = nN * IN_DIM / 4;
  k_pre<<<769 + (n4 + 255) / 256, 256, 0, stream>>>((const unsigned int*)ei, flag,
                                                    w1l, w1r, W1c, w2l, w2r, W2c,
                                                    x, xbf, n4);
  k_deg<<<(nE + 255) / 256, 256, 0, stream>>>(ei, nE, flag, deg);
  k_bsum<<<nb, 256, 0, stream>>>(deg, bsum);
  k_bscan<<<1, 1024, 0, stream>>>(bsum, nb);
  k_offsets<<<nb, 256, 0, stream>>>(deg, bsum, offs, cursor);
  k_fill<<<(nE + 255) / 256, 256, 0, stream>>>(ei, nE, flag, cursor, csr);

  dim3 g1(512 / 128, Mpad / 128);
  k_gemm1<<<g1, 256, 0, stream>>>(xbf, W1c, Cl, Cr, b1);
  k_agg1<<<(nN + 3) / 4, 256, 0, stream>>>(Cl, Cr, offs, csr, hbuf, nN);
  k_agg2<<<(nN + 3) / 4, 256, 0, stream>>>(hbuf, offs, csr, mean2, nN);
  k_gemm2<<<g1, 256, 0, stream>>>(mean2, hbuf, W2c, out, b2, nN);
}

// Round 2
// 667.711 us; speedup vs baseline: 1.1303x; 1.0101x over previous
//
#include <hip/hip_runtime.h>

// GraphSAGE 2-layer encoder, MI355X (gfx950).  Round 4.
// vs R3: k_deg fused into k_pre (atomics hide under the 307MB streaming pass,
// per-block dtype re-detect removes flag dependency); agg gathers use an
// 8/4/2/1-pair batch cascade (up to 16 rows = 8KB in flight per wave, no
// serial single-pair tail at typical degree 16).
//   GEMM1: Cl = x@w1_l^T ; Cr = x@w1_r^T + b1          (bf16, [Mpad,256] each)
//   agg1 : h[n] = relu(mean(Cl[src]) + Cr[n])          (bf16 [Mpad,256])
//   agg2 : mean2[n] = mean(h[src])                     (bf16 [Mpad,256])
//   GEMM2: out = [mean2|h] @ [w2_l|w2_r]^T + b2        (fp32 [nN,512])

#define IN_DIM  1024
#define HID_DIM 256
#define OUT_N   512

typedef __attribute__((ext_vector_type(8))) short bf16x8;
typedef __attribute__((ext_vector_type(4))) float f32x4;

static __device__ __forceinline__ unsigned short f2bf(float f) {
  unsigned int u = __float_as_uint(f);
  u += 0x7fffu + ((u >> 16) & 1u);
  return (unsigned short)(u >> 16);
}
static __device__ __forceinline__ float bf2f(unsigned short b) {
  return __uint_as_float(((unsigned int)b) << 16);
}

static __device__ __forceinline__ int load_idx(const void* ei, long long pos, int is64) {
  if (is64) return (int)((const long long*)ei)[pos];
  return ((const int*)ei)[pos];
}

// ---------- fused: dtype detect + weight cvt + x cvt + degree count ----------
// block 0: detect->flag; [1,513): w1cat; [513,769): w2cat;
// [769, 769+nxb): cvt x; [769+nxb, 769+nxb+nEb): degree atomics (own detect).
__global__ void k_pre(const unsigned int* __restrict__ eiu, const void* __restrict__ ei,
                      int* __restrict__ flag,
                      const float* __restrict__ w1l, const float* __restrict__ w1r,
                      unsigned short* __restrict__ W1c,
                      const float* __restrict__ w2l, const float* __restrict__ w2r,
                      unsigned short* __restrict__ W2c,
                      const float* __restrict__ x, unsigned short* __restrict__ xbf,
                      int n4, int nxb, int nE, int* __restrict__ deg) {
  int b = blockIdx.x;
  if (b == 0) {
    if (threadIdx.x < 64) {
      unsigned int v = eiu[2 * threadIdx.x + 1];
      unsigned long long m = __ballot(v == 0u);
      if (threadIdx.x == 0) *flag = (m == ~0ull) ? 1 : 0;
    }
    return;
  }
  if (b < 513) {                      // W1cat[n][k], n<256 -> w1_l else w1_r; K=1024
    int i = (b - 1) * 256 + threadIdx.x;
    int base = i * 4;
    int n = base / IN_DIM, k = base % IN_DIM;
    const float* s = (n < HID_DIM) ? &w1l[(size_t)n * IN_DIM + k]
                                   : &w1r[(size_t)(n - HID_DIM) * IN_DIM + k];
    float4 v = *(const float4*)s;
    ushort4 o = { f2bf(v.x), f2bf(v.y), f2bf(v.z), f2bf(v.w) };
    *(ushort4*)&W1c[base] = o;
    return;
  }
  if (b < 769) {                      // W2cat[n][k], k<256 -> w2_l else w2_r; K=512
    int i = (b - 513) * 256 + threadIdx.x;
    int base = i * 4;
    int n = base >> 9, k = base & 511;
    const float* s = (k < HID_DIM) ? &w2l[(size_t)n * HID_DIM + k]
                                   : &w2r[(size_t)n * HID_DIM + (k - HID_DIM)];
    float4 v = *(const float4*)s;
    ushort4 o = { f2bf(v.x), f2bf(v.y), f2bf(v.z), f2bf(v.w) };
    *(ushort4*)&W2c[base] = o;
    return;
  }
  if (b < 769 + nxb) {                // x -> bf16
    int i = (b - 769) * 256 + threadIdx.x;
    if (i >= n4) return;
    float4 v = ((const float4*)x)[i];
    ushort4 o = { f2bf(v.x), f2bf(v.y), f2bf(v.z), f2bf(v.w) };
    ((ushort4*)xbf)[i] = o;
    return;
  }
  // degree count (per-block dtype detect: no dependency on block 0)
  __shared__ int s_is64;
  if (threadIdx.x < 64) {
    unsigned int v = eiu[2 * threadIdx.x + 1];
    unsigned long long m = __ballot(v == 0u);
    if (threadIdx.x == 0) s_is64 = (m == ~0ull) ? 1 : 0;
  }
  __syncthreads();
  int e = (b - 769 - nxb) * 256 + threadIdx.x;
  if (e < nE) {
    int d = load_idx(ei, (long long)nE + e, s_is64);
    atomicAdd(&deg[d], 1);
  }
}

// ---------- CSR build ----------
// block b sums deg[b*1024 .. b*1024+1024) -> bsum[b]   (deg zero-padded to 1024)
__global__ void k_bsum(const int* __restrict__ deg, int* __restrict__ bsum) {
  int t = threadIdx.x;
  int4 d4 = ((const int4*)(deg + (size_t)blockIdx.x * 1024))[t];
  int v = d4.x + d4.y + d4.z + d4.w;
#pragma unroll
  for (int d = 1; d < 64; d <<= 1) v += __shfl_xor(v, d);
  __shared__ int ws[4];
  if ((t & 63) == 0) ws[t >> 6] = v;
  __syncthreads();
  if (t == 0) bsum[blockIdx.x] = ws[0] + ws[1] + ws[2] + ws[3];
}

// inclusive scan of bsum[0..nb), nb <= 1024
__global__ __launch_bounds__(1024) void k_bscan(int* __restrict__ bsum, int nb) {
  __shared__ int s[1024];
  int t = threadIdx.x;
  s[t] = (t < nb) ? bsum[t] : 0;
  __syncthreads();
  for (int d = 1; d < 1024; d <<= 1) {
    int v = (t >= d) ? s[t - d] : 0;
    __syncthreads();
    s[t] += v;
    __syncthreads();
  }
  if (t < nb) bsum[t] = s[t];
}

// block b: exclusive scan of its 1024 degs + block prefix -> off[] and cursor[]
__global__ __launch_bounds__(256) void k_offsets(const int* __restrict__ deg,
                                                 const int* __restrict__ bsumInc,
                                                 int* __restrict__ off,
                                                 int* __restrict__ cursor) {
  const int t = threadIdx.x;
  const int l = t & 63, w = t >> 6;
  const size_t base = (size_t)blockIdx.x * 1024;
  int4 d4 = ((const int4*)(deg + base))[t];
  int tsum = d4.x + d4.y + d4.z + d4.w;
  int incl = tsum;
#pragma unroll
  for (int d = 1; d < 64; d <<= 1) {
    int u = __shfl_up(incl, d);
    if (l >= d) incl += u;
  }
  __shared__ int wt[4];
  if (l == 63) wt[w] = incl;
  __syncthreads();
  int wpre = 0;
  for (int i = 0; i < w; ++i) wpre += wt[i];
  int bpre = (blockIdx.x == 0) ? 0 : bsumInc[blockIdx.x - 1];
  int excl = bpre + wpre + incl - tsum;
  int4 o;
  o.x = excl;
  o.y = excl + d4.x;
  o.z = o.y + d4.y;
  o.w = o.z + d4.z;
  ((int4*)(off + base))[t] = o;
  ((int4*)(cursor + base))[t] = o;
}

__global__ void k_fill(const void* ei, int nE, const int* flag,
                       int* cursor, int* __restrict__ csr) {
  int e = blockIdx.x * 256 + threadIdx.x;
  if (e >= nE) return;
  int is64 = *flag;
  int s = load_idx(ei, e, is64);
  int d = load_idx(ei, (long long)nE + e, is64);
  int p = atomicAdd(&cursor[d], 1);
  csr[p] = s;
}

// ---------- GEMMs (m97-style: 128x128 tile, BK=32, 4 waves 2x2, 4x4 mfma) ----------
static __device__ __forceinline__ void load_lds16(const void* g, void* lds) {
  __builtin_amdgcn_global_load_lds(
      (const __attribute__((address_space(1))) unsigned int*)g,
      (__attribute__((address_space(3))) unsigned int*)lds, 16, 0, 0);
}

// bijective XCD-chunk swizzle (m204): consecutive logical tiles land on one XCD
static __device__ __forceinline__ int xcd_swz(int orig, int nwg) {
  const int q = nwg >> 3, r = nwg & 7;
  const int xcd = orig & 7, rk = orig >> 3;
  return (xcd < r) ? xcd * (q + 1) + rk : r * (q + 1) + (xcd - r) * q + rk;
}

// GEMM1: A=[Mpad,1024] bf16, B=W1c[512,1024] bf16; out split Cl/Cr (+b1 on right)
__global__ __launch_bounds__(256) void k_gemm1(const unsigned short* __restrict__ A,
                                               const unsigned short* __restrict__ B,
                                               unsigned short* __restrict__ Cl,
                                               unsigned short* __restrict__ Cr,
                                               const float* __restrict__ b1) {
  __shared__ unsigned short As[128 * 32];
  __shared__ unsigned short Bs[128 * 32];
  const int tid = threadIdx.x;
  const int w = tid >> 6, l = tid & 63;
  const int wm = w >> 1, wn = w & 1;
  const int quad = l >> 4, lane16 = l & 15;
  const int nwg = gridDim.x * gridDim.y;
  const int wg = xcd_swz(blockIdx.y * gridDim.x + blockIdx.x, nwg);
  const int m0 = (wg / gridDim.x) * 128;
  const int n0 = (wg % gridDim.x) * 128;

  f32x4 acc[4][4] = {};
  for (int k0 = 0; k0 < IN_DIM; k0 += 32) {
#pragma unroll
    for (int c = 0; c < 2; ++c) {
      const int flat = ((w * 2 + c) << 10);
      const int fb = flat + l * 16;
      const int row = fb >> 6;
      const int cb = fb & 63;
      load_lds16(A + (size_t)(m0 + row) * IN_DIM + (k0 + (cb >> 1)), (char*)As + flat);
      load_lds16(B + (size_t)(n0 + row) * IN_DIM + (k0 + (cb >> 1)), (char*)Bs + flat);
    }
    __syncthreads();
    bf16x8 af[4], bfr[4];
#pragma unroll
    for (int i = 0; i < 4; ++i)
      af[i] = *(const bf16x8*)&As[(wm * 64 + i * 16 + lane16) * 32 + quad * 8];
#pragma unroll
    for (int j = 0; j < 4; ++j)
      bfr[j] = *(const bf16x8*)&Bs[(wn * 64 + j * 16 + lane16) * 32 + quad * 8];
#pragma unroll
    for (int i = 0; i < 4; ++i)
#pragma unroll
      for (int j = 0; j < 4; ++j)
        acc[i][j] = __builtin_amdgcn_mfma_f32_16x16x32_bf16(af[i], bfr[j], acc[i][j], 0, 0, 0);
    __syncthreads();
  }

  const bool right = (n0 >= 256);
  unsigned short* Cb = right ? Cr : Cl;
  const int nc0 = n0 - (right ? 256 : 0);
#pragma unroll
  for (int i = 0; i < 4; ++i) {
    const int rbase = m0 + wm * 64 + i * 16 + quad * 4;
#pragma unroll
    for (int j = 0; j < 4; ++j) {
      const int col = nc0 + wn * 64 + j * 16 + lane16;
      const float bv = right ? b1[col] : 0.0f;
#pragma unroll
      for (int r = 0; r < 4; ++r)
        Cb[(size_t)(rbase + r) * HID_DIM + col] = f2bf(acc[i][j][r] + bv);
    }
  }
}

// GEMM2: A k<256 from Am (mean2), k>=256 from Ah (h); B=W2c[512,512]; fp32 out + b2
__global__ __launch_bounds__(256) void k_gemm2(const unsigned short* __restrict__ Am,
                                               const unsigned short* __restrict__ Ah,
                                               const unsigned short* __restrict__ B,
                                               float* __restrict__ out,
                                               const float* __restrict__ b2, int Mstore) {
  __shared__ unsigned short As[128 * 32];
  __shared__ unsigned short Bs[128 * 32];
  const int tid = threadIdx.x;
  const int w = tid >> 6, l = tid & 63;
  const int wm = w >> 1, wn = w & 1;
  const int quad = l >> 4, lane16 = l & 15;
  const int nwg = gridDim.x * gridDim.y;
  const int wg = xcd_swz(blockIdx.y * gridDim.x + blockIdx.x, nwg);
  const int m0 = (wg / gridDim.x) * 128;
  const int n0 = (wg % gridDim.x) * 128;

  f32x4 acc[4][4] = {};
  for (int k0 = 0; k0 < 2 * HID_DIM; k0 += 32) {
    const unsigned short* Abase = (k0 < HID_DIM) ? Am + k0 : Ah + (k0 - HID_DIM);
#pragma unroll
    for (int c = 0; c < 2; ++c) {
      const int flat = ((w * 2 + c) << 10);
      const int fb = flat + l * 16;
      const int row = fb >> 6;
      const int cb = fb & 63;
      load_lds16(Abase + (size_t)(m0 + row) * HID_DIM + (cb >> 1), (char*)As + flat);
      load_lds16(B + (size_t)(n0 + row) * (2 * HID_DIM) + (k0 + (cb >> 1)), (char*)Bs + flat);
    }
    __syncthreads();
    bf16x8 af[4], bfr[4];
#pragma unroll
    for (int i = 0; i < 4; ++i)
      af[i] = *(const bf16x8*)&As[(wm * 64 + i * 16 + lane16) * 32 + quad * 8];
#pragma unroll
    for (int j = 0; j < 4; ++j)
      bfr[j] = *(const bf16x8*)&Bs[(wn * 64 + j * 16 + lane16) * 32 + quad * 8];
#pragma unroll
    for (int i = 0; i < 4; ++i)
#pragma unroll
      for (int j = 0; j < 4; ++j)
        acc[i][j] = __builtin_amdgcn_mfma_f32_16x16x32_bf16(af[i], bfr[j], acc[i][j], 0, 0, 0);
    __syncthreads();
  }

#pragma unroll
  for (int i = 0; i < 4; ++i) {
    const int rbase = m0 + wm * 64 + i * 16 + quad * 4;
#pragma unroll
    for (int j = 0; j < 4; ++j) {
      const int col = n0 + wn * 64 + j * 16 + lane16;
      const float bv = b2[col];
#pragma unroll
      for (int r = 0; r < 4; ++r) {
        const int rowi = rbase + r;
        if (rowi < Mstore) out[(size_t)rowi * OUT_N + col] = acc[i][j][r] + bv;
      }
    }
  }
}

// ---------- aggregations: 1 wave/node, 16B/lane, 8/4/2/1-pair batch cascade ----------
// half h (lanes h*32..) reads row of edge s+2k+h; batch of NB pairs keeps 2*NB
// rows (up to 8KB) in flight.
template <int NB>
static __device__ __forceinline__ void gatherN(const unsigned short* __restrict__ src,
                                               const int* __restrict__ csr, int ib,
                                               size_t colb, float* a) {
  bf16x8 v[NB];
#pragma unroll
  for (int u = 0; u < NB; ++u) {
    int r = csr[ib + 2 * u];
    v[u] = *(const bf16x8*)&src[(size_t)r * HID_DIM + colb];
  }
#pragma unroll
  for (int u = 0; u < NB; ++u)
#pragma unroll
    for (int c = 0; c < 8; ++c) a[c] += bf2f((unsigned short)v[u][c]);
}

static __device__ __forceinline__ void agg_sum(const unsigned short* __restrict__ src,
                                               const int* __restrict__ csr,
                                               int s, int e, int half, size_t colb,
                                               float* a) {
  const int cnt = e - s;
  const int P = cnt >> 1;
  const int ib0 = s + half;
  int k = 0;
  for (; k + 8 <= P; k += 8) gatherN<8>(src, csr, ib0 + 2 * k, colb, a);
  if (k + 4 <= P) { gatherN<4>(src, csr, ib0 + 2 * k, colb, a); k += 4; }
  if (k + 2 <= P) { gatherN<2>(src, csr, ib0 + 2 * k, colb, a); k += 2; }
  if (k < P)      { gatherN<1>(src, csr, ib0 + 2 * k, colb, a); }
  if ((cnt & 1) && half == 0) {
    bf16x8 v = *(const bf16x8*)&src[(size_t)csr[e - 1] * HID_DIM + colb];
#pragma unroll
    for (int c = 0; c < 8; ++c) a[c] += bf2f((unsigned short)v[c]);
  }
#pragma unroll
  for (int c = 0; c < 8; ++c) a[c] += __shfl_xor(a[c], 32);
}

__global__ void k_agg1(const unsigned short* __restrict__ Cl,
                       const unsigned short* __restrict__ Cr,
                       const int* __restrict__ off, const int* __restrict__ csr,
                       unsigned short* __restrict__ h, int nNodes) {
  int node = blockIdx.x * 4 + (threadIdx.x >> 6);
  if (node >= nNodes) return;
  const int l = threadIdx.x & 63;
  const int half = l >> 5, li = l & 31;
  const size_t colb = (size_t)li * 8;
  int s = off[node], e = off[node + 1];
  float a[8] = {};
  agg_sum(Cl, csr, s, e, half, colb, a);
  if (half == 0) {
    float inv = 1.0f / fmaxf((float)(e - s), 1.0f);
    bf16x8 xr = *(const bf16x8*)&Cr[(size_t)node * HID_DIM + colb];   // includes b1
    bf16x8 o;
#pragma unroll
    for (int c = 0; c < 8; ++c)
      o[c] = (short)f2bf(fmaxf(a[c] * inv + bf2f((unsigned short)xr[c]), 0.0f));
    *(bf16x8*)&h[(size_t)node * HID_DIM + colb] = o;
  }
}

__global__ void k_agg2(const unsigned short* __restrict__ hsrc,
                       const int* __restrict__ off, const int* __restrict__ csr,
                       unsigned short* __restrict__ mean2, int nNodes) {
  int node = blockIdx.x * 4 + (threadIdx.x >> 6);
  if (node >= nNodes) return;
  const int l = threadIdx.x & 63;
  const int half = l >> 5, li = l & 31;
  const size_t colb = (size_t)li * 8;
  int s = off[node], e = off[node + 1];
  float a[8] = {};
  agg_sum(hsrc, csr, s, e, half, colb, a);
  if (half == 0) {
    float inv = 1.0f / fmaxf((float)(e - s), 1.0f);
    bf16x8 o;
#pragma unroll
    for (int c = 0; c < 8; ++c) o[c] = (short)f2bf(a[c] * inv);
    *(bf16x8*)&mean2[(size_t)node * HID_DIM + colb] = o;
  }
}

extern "C" void kernel_launch(void* const* d_in, const int* in_sizes, int n_in,
                              void* d_out, int out_size, void* d_ws, size_t ws_size,
                              hipStream_t stream) {
  const float* x   = (const float*)d_in[0];
  const void*  ei  = d_in[1];
  const float* w1l = (const float*)d_in[2];
  const float* w1r = (const float*)d_in[3];
  const float* b1  = (const float*)d_in[4];
  const float* w2l = (const float*)d_in[5];
  const float* w2r = (const float*)d_in[6];
  const float* b2  = (const float*)d_in[7];
  float* out = (float*)d_out;

  const int nN   = in_sizes[0] / IN_DIM;         // 50000
  const int nE   = in_sizes[1] / 2;              // 800000
  const int Mpad = (nN + 127) & ~127;            // 50048
  const int padN = (nN + 1023) & ~1023;          // 50176 (scan granularity)
  const int nb   = padN >> 10;                   // 49 scan blocks

  char* ws = (char*)d_ws;
  size_t o = 0;
  auto alloc = [&](size_t bytes) {
    char* p = ws + o;
    o += (bytes + 255) & ~(size_t)255;
    return p;
  };
  unsigned short* xbf   = (unsigned short*)alloc((size_t)Mpad * IN_DIM * 2);
  unsigned short* W1c   = (unsigned short*)alloc((size_t)2 * HID_DIM * IN_DIM * 2);
  unsigned short* W2c   = (unsigned short*)alloc((size_t)OUT_N * 2 * HID_DIM * 2);
  unsigned short* Cl    = (unsigned short*)alloc((size_t)Mpad * HID_DIM * 2);
  unsigned short* Cr    = (unsigned short*)alloc((size_t)Mpad * HID_DIM * 2);
  unsigned short* hbuf  = (unsigned short*)alloc((size_t)Mpad * HID_DIM * 2);
  unsigned short* mean2 = (unsigned short*)alloc((size_t)Mpad * HID_DIM * 2);
  int* deg    = (int*)alloc((size_t)padN * 4);         // zero-padded for int4 scan
  int* offs   = (int*)alloc((size_t)padN * 4);         // off[nN]=nE lands in pad region
  int* cursor = (int*)alloc((size_t)padN * 4);
  int* bsum   = (int*)alloc((size_t)1024 * 4);
  int* csr    = (int*)alloc((size_t)nE * 4);
  int* flag   = (int*)alloc(256);

  hipMemsetAsync(deg, 0, (size_t)padN * 4, stream);
  // pad rows of xbf / hbuf / mean2 stay 0xAA poison: decodes to ~1e-13 bf16,
  // flows only into pad rows of Cl/Cr/out-guarded stores -> never observed.

  const int n4  = nN * IN_DIM / 4;
  const int nxb = (n4 + 255) / 256;
  const int nEb = (nE + 255) / 256;
  k_pre<<<769 + nxb + nEb, 256, 0, stream>>>((const unsigned int*)ei, ei, flag,
                                             w1l, w1r, W1c, w2l, w2r, W2c,
                                             x, xbf, n4, nxb, nE, deg);
  k_bsum<<<nb, 256, 0, stream>>>(deg, bsum);
  k_bscan<<<1, 1024, 0, stream>>>(bsum, nb);
  k_offsets<<<nb, 256, 0, stream>>>(deg, bsum, offs, cursor);
  k_fill<<<(nE + 255) / 256, 256, 0, stream>>>(ei, nE, flag, cursor, csr);

  dim3 g1(512 / 128, Mpad / 128);
  k_gemm1<<<g1, 256, 0, stream>>>(xbf, W1c, Cl, Cr, b1);
  k_agg1<<<(nN + 3) / 4, 256, 0, stream>>>(Cl, Cr, offs, csr, hbuf, nN);
  k_agg2<<<(nN + 3) / 4, 256, 0, stream>>>(hbuf, offs, csr, mean2, nN);
  k_gemm2<<<g1, 256, 0, stream>>>(mean2, hbuf, W2c, out, b2, nN);
}

// Round 3
// 654.925 us; speedup vs baseline: 1.1524x; 1.0195x over previous
//
#include <hip/hip_runtime.h>

// GraphSAGE 2-layer encoder, MI355X (gfx950).  Round 5.
// vs R4: xbf eliminated (gemm1 reads fp32 x directly, cvt in A-staging; saves
// ~200MB HBM round-trip); k_fill fused into gemm1's dispatch as trailing
// blocks (scatter atomics hide under GEMM); 3-kernel scan collapsed into one
// single-block kernel.  10 -> 7 dispatches.
//   GEMM1: Cl = x@w1_l^T ; Cr = x@w1_r^T + b1          (bf16, [Mpad,256] each)
//   agg1 : h[n] = relu(mean(Cl[src]) + Cr[n])          (bf16 [Mpad,256])
//   agg2 : mean2[n] = mean(h[src])                     (bf16 [Mpad,256])
//   GEMM2: out = [mean2|h] @ [w2_l|w2_r]^T + b2        (fp32 [nN,512])

#define IN_DIM  1024
#define HID_DIM 256
#define OUT_N   512

typedef __attribute__((ext_vector_type(8))) short bf16x8;
typedef __attribute__((ext_vector_type(4))) float f32x4;

static __device__ __forceinline__ unsigned short f2bf(float f) {
  unsigned int u = __float_as_uint(f);
  u += 0x7fffu + ((u >> 16) & 1u);
  return (unsigned short)(u >> 16);
}
static __device__ __forceinline__ float bf2f(unsigned short b) {
  return __uint_as_float(((unsigned int)b) << 16);
}

static __device__ __forceinline__ int load_idx(const void* ei, long long pos, int is64) {
  if (is64) return (int)((const long long*)ei)[pos];
  return ((const int*)ei)[pos];
}

// ---------- fused: dtype detect + weight cvt + degree count ----------
// block 0: detect->flag; [1,513): w1cat; [513,769): w2cat;
// [769, 769+nEb): degree atomics (own per-block detect).
__global__ void k_pre(const unsigned int* __restrict__ eiu, const void* __restrict__ ei,
                      int* __restrict__ flag,
                      const float* __restrict__ w1l, const float* __restrict__ w1r,
                      unsigned short* __restrict__ W1c,
                      const float* __restrict__ w2l, const float* __restrict__ w2r,
                      unsigned short* __restrict__ W2c,
                      int nE, int* __restrict__ deg) {
  int b = blockIdx.x;
  if (b == 0) {
    if (threadIdx.x < 64) {
      unsigned int v = eiu[2 * threadIdx.x + 1];
      unsigned long long m = __ballot(v == 0u);
      if (threadIdx.x == 0) *flag = (m == ~0ull) ? 1 : 0;
    }
    return;
  }
  if (b < 513) {                      // W1cat[n][k], n<256 -> w1_l else w1_r; K=1024
    int i = (b - 1) * 256 + threadIdx.x;
    int base = i * 4;
    int n = base / IN_DIM, k = base % IN_DIM;
    const float* s = (n < HID_DIM) ? &w1l[(size_t)n * IN_DIM + k]
                                   : &w1r[(size_t)(n - HID_DIM) * IN_DIM + k];
    float4 v = *(const float4*)s;
    ushort4 o = { f2bf(v.x), f2bf(v.y), f2bf(v.z), f2bf(v.w) };
    *(ushort4*)&W1c[base] = o;
    return;
  }
  if (b < 769) {                      // W2cat[n][k], k<256 -> w2_l else w2_r; K=512
    int i = (b - 513) * 256 + threadIdx.x;
    int base = i * 4;
    int n = base >> 9, k = base & 511;
    const float* s = (k < HID_DIM) ? &w2l[(size_t)n * HID_DIM + k]
                                   : &w2r[(size_t)n * HID_DIM + (k - HID_DIM)];
    float4 v = *(const float4*)s;
    ushort4 o = { f2bf(v.x), f2bf(v.y), f2bf(v.z), f2bf(v.w) };
    *(ushort4*)&W2c[base] = o;
    return;
  }
  // degree count (per-block dtype detect: no dependency on block 0)
  __shared__ int s_is64;
  if (threadIdx.x < 64) {
    unsigned int v = eiu[2 * threadIdx.x + 1];
    unsigned long long m = __ballot(v == 0u);
    if (threadIdx.x == 0) s_is64 = (m == ~0ull) ? 1 : 0;
  }
  __syncthreads();
  int e = (b - 769) * 256 + threadIdx.x;
  if (e < nE) {
    int d = load_idx(ei, (long long)nE + e, s_is64);
    atomicAdd(&deg[d], 1);
  }
}

// ---------- single-block exclusive scan: deg[padN] -> off[], cursor[] ----------
__global__ __launch_bounds__(1024) void k_scan1(const int* __restrict__ deg,
                                                int* __restrict__ off,
                                                int* __restrict__ cursor, int n4q) {
  const int t = threadIdx.x;
  const int CH = (n4q + 1023) >> 10;    // int4s per thread (13 at padN=50176)
  const int i0 = t * CH;
  int tsum = 0;
  for (int i = 0; i < CH; ++i) {
    int idx = i0 + i;
    if (idx < n4q) {
      int4 d = ((const int4*)deg)[idx];
      tsum += d.x + d.y + d.z + d.w;
    }
  }
  __shared__ int s[1024];
  s[t] = tsum;
  __syncthreads();
  for (int d = 1; d < 1024; d <<= 1) {
    int u = (t >= d) ? s[t - d] : 0;
    __syncthreads();
    s[t] += u;
    __syncthreads();
  }
  int run = (t == 0) ? 0 : s[t - 1];
  for (int i = 0; i < CH; ++i) {
    int idx = i0 + i;
    if (idx < n4q) {
      int4 d = ((const int4*)deg)[idx];
      int4 o;
      o.x = run;
      o.y = run + d.x;
      o.z = o.y + d.y;
      o.w = o.z + d.z;
      run = o.w + d.w;
      ((int4*)off)[idx] = o;
      ((int4*)cursor)[idx] = o;
    }
  }
}

// ---------- GEMM helpers ----------
static __device__ __forceinline__ void load_lds16(const void* g, void* lds) {
  __builtin_amdgcn_global_load_lds(
      (const __attribute__((address_space(1))) unsigned int*)g,
      (__attribute__((address_space(3))) unsigned int*)lds, 16, 0, 0);
}

// bijective XCD-chunk swizzle (m204): consecutive logical tiles land on one XCD
static __device__ __forceinline__ int xcd_swz(int orig, int nwg) {
  const int q = nwg >> 3, r = nwg & 7;
  const int xcd = orig & 7, rk = orig >> 3;
  return (xcd < r) ? xcd * (q + 1) + rk : r * (q + 1) + (xcd - r) * q + rk;
}

// ---------- fused GEMM1 + csr fill ----------
// blocks [0, ngemm): gemm1 tiles (1D, wg>>2 = m-tile, wg&3 = n-tile);
// blocks [ngemm, ...): csr fill (independent of gemm1; consumer agg1 is the
// next dispatch on the stream).
// A is fp32 x (unpadded, rows clamped); numerics identical to the old
// xbf path (same f2bf round during staging).
__global__ __launch_bounds__(256) void k_g1f(const float* __restrict__ A,
                                             const unsigned short* __restrict__ B,
                                             unsigned short* __restrict__ Cl,
                                             unsigned short* __restrict__ Cr,
                                             const float* __restrict__ b1,
                                             int nNm1, int ngemm,
                                             const void* __restrict__ ei, int nE,
                                             const int* __restrict__ flag,
                                             int* __restrict__ cursor,
                                             int* __restrict__ csr) {
  if ((int)blockIdx.x >= ngemm) {     // ---- csr fill path ----
    int e = ((int)blockIdx.x - ngemm) * 256 + threadIdx.x;
    if (e < nE) {
      int is64 = *flag;
      int s = load_idx(ei, e, is64);
      int d = load_idx(ei, (long long)nE + e, is64);
      int p = atomicAdd(&cursor[d], 1);
      csr[p] = s;
    }
    return;
  }
  __shared__ unsigned short As[128 * 32];
  __shared__ unsigned short Bs[128 * 32];
  const int tid = threadIdx.x;
  const int w = tid >> 6, l = tid & 63;
  const int wm = w >> 1, wn = w & 1;
  const int quad = l >> 4, lane16 = l & 15;
  const int wg = xcd_swz(blockIdx.x, ngemm);
  const int m0 = (wg >> 2) * 128;
  const int n0 = (wg & 3) * 128;

  // hoisted, clamped A row base pointers (row is per-thread constant over K)
  const float* ap[4];
#pragma unroll
  for (int it = 0; it < 4; ++it) {
    const int eidx = it * 1024 + tid * 4;       // element in 128x32 tile
    int ar = m0 + (eidx >> 5);
    if (ar > nNm1) ar = nNm1;                   // pad rows: dup of last real row,
    ap[it] = A + (size_t)ar * IN_DIM + (eidx & 31);  // lands only in unread pad C rows
  }

  f32x4 acc[4][4] = {};
  for (int k0 = 0; k0 < IN_DIM; k0 += 32) {
#pragma unroll
    for (int it = 0; it < 4; ++it) {            // A: fp32 -> bf16 reg-staged
      const int eidx = it * 1024 + tid * 4;
      float4 v = *(const float4*)(ap[it] + k0);
      ushort4 o = { f2bf(v.x), f2bf(v.y), f2bf(v.z), f2bf(v.w) };
      *(ushort4*)&As[eidx] = o;
    }
#pragma unroll
    for (int c = 0; c < 2; ++c) {               // B: global_load_lds 16B
      const int flat = ((w * 2 + c) << 10);
      const int fb = flat + l * 16;
      const int row = fb >> 6;
      const int cb = fb & 63;
      load_lds16(B + (size_t)(n0 + row) * IN_DIM + (k0 + (cb >> 1)), (char*)Bs + flat);
    }
    __syncthreads();
    bf16x8 af[4], bfr[4];
#pragma unroll
    for (int i = 0; i < 4; ++i)
      af[i] = *(const bf16x8*)&As[(wm * 64 + i * 16 + lane16) * 32 + quad * 8];
#pragma unroll
    for (int j = 0; j < 4; ++j)
      bfr[j] = *(const bf16x8*)&Bs[(wn * 64 + j * 16 + lane16) * 32 + quad * 8];
#pragma unroll
    for (int i = 0; i < 4; ++i)
#pragma unroll
      for (int j = 0; j < 4; ++j)
        acc[i][j] = __builtin_amdgcn_mfma_f32_16x16x32_bf16(af[i], bfr[j], acc[i][j], 0, 0, 0);
    __syncthreads();
  }

  const bool right = (n0 >= 256);
  unsigned short* Cb = right ? Cr : Cl;
  const int nc0 = n0 - (right ? 256 : 0);
#pragma unroll
  for (int i = 0; i < 4; ++i) {
    const int rbase = m0 + wm * 64 + i * 16 + quad * 4;
#pragma unroll
    for (int j = 0; j < 4; ++j) {
      const int col = nc0 + wn * 64 + j * 16 + lane16;
      const float bv = right ? b1[col] : 0.0f;
#pragma unroll
      for (int r = 0; r < 4; ++r)
        Cb[(size_t)(rbase + r) * HID_DIM + col] = f2bf(acc[i][j][r] + bv);
    }
  }
}

// GEMM2: A k<256 from Am (mean2), k>=256 from Ah (h); B=W2c[512,512]; fp32 out + b2
__global__ __launch_bounds__(256) void k_gemm2(const unsigned short* __restrict__ Am,
                                               const unsigned short* __restrict__ Ah,
                                               const unsigned short* __restrict__ B,
                                               float* __restrict__ out,
                                               const float* __restrict__ b2, int Mstore) {
  __shared__ unsigned short As[128 * 32];
  __shared__ unsigned short Bs[128 * 32];
  const int tid = threadIdx.x;
  const int w = tid >> 6, l = tid & 63;
  const int wm = w >> 1, wn = w & 1;
  const int quad = l >> 4, lane16 = l & 15;
  const int nwg = gridDim.x * gridDim.y;
  const int wg = xcd_swz(blockIdx.y * gridDim.x + blockIdx.x, nwg);
  const int m0 = (wg / gridDim.x) * 128;
  const int n0 = (wg % gridDim.x) * 128;

  f32x4 acc[4][4] = {};
  for (int k0 = 0; k0 < 2 * HID_DIM; k0 += 32) {
    const unsigned short* Abase = (k0 < HID_DIM) ? Am + k0 : Ah + (k0 - HID_DIM);
#pragma unroll
    for (int c = 0; c < 2; ++c) {
      const int flat = ((w * 2 + c) << 10);
      const int fb = flat + l * 16;
      const int row = fb >> 6;
      const int cb = fb & 63;
      load_lds16(Abase + (size_t)(m0 + row) * HID_DIM + (cb >> 1), (char*)As + flat);
      load_lds16(B + (size_t)(n0 + row) * (2 * HID_DIM) + (k0 + (cb >> 1)), (char*)Bs + flat);
    }
    __syncthreads();
    bf16x8 af[4], bfr[4];
#pragma unroll
    for (int i = 0; i < 4; ++i)
      af[i] = *(const bf16x8*)&As[(wm * 64 + i * 16 + lane16) * 32 + quad * 8];
#pragma unroll
    for (int j = 0; j < 4; ++j)
      bfr[j] = *(const bf16x8*)&Bs[(wn * 64 + j * 16 + lane16) * 32 + quad * 8];
#pragma unroll
    for (int i = 0; i < 4; ++i)
#pragma unroll
      for (int j = 0; j < 4; ++j)
        acc[i][j] = __builtin_amdgcn_mfma_f32_16x16x32_bf16(af[i], bfr[j], acc[i][j], 0, 0, 0);
    __syncthreads();
  }

#pragma unroll
  for (int i = 0; i < 4; ++i) {
    const int rbase = m0 + wm * 64 + i * 16 + quad * 4;
#pragma unroll
    for (int j = 0; j < 4; ++j) {
      const int col = n0 + wn * 64 + j * 16 + lane16;
      const float bv = b2[col];
#pragma unroll
      for (int r = 0; r < 4; ++r) {
        const int rowi = rbase + r;
        if (rowi < Mstore) out[(size_t)rowi * OUT_N + col] = acc[i][j][r] + bv;
      }
    }
  }
}

// ---------- aggregations: 1 wave/node, 16B/lane, 8/4/2/1-pair batch cascade ----------
template <int NB>
static __device__ __forceinline__ void gatherN(const unsigned short* __restrict__ src,
                                               const int* __restrict__ csr, int ib,
                                               size_t colb, float* a) {
  bf16x8 v[NB];
#pragma unroll
  for (int u = 0; u < NB; ++u) {
    int r = csr[ib + 2 * u];
    v[u] = *(const bf16x8*)&src[(size_t)r * HID_DIM + colb];
  }
#pragma unroll
  for (int u = 0; u < NB; ++u)
#pragma unroll
    for (int c = 0; c < 8; ++c) a[c] += bf2f((unsigned short)v[u][c]);
}

static __device__ __forceinline__ void agg_sum(const unsigned short* __restrict__ src,
                                               const int* __restrict__ csr,
                                               int s, int e, int half, size_t colb,
                                               float* a) {
  const int cnt = e - s;
  const int P = cnt >> 1;
  const int ib0 = s + half;
  int k = 0;
  for (; k + 8 <= P; k += 8) gatherN<8>(src, csr, ib0 + 2 * k, colb, a);
  if (k + 4 <= P) { gatherN<4>(src, csr, ib0 + 2 * k, colb, a); k += 4; }
  if (k + 2 <= P) { gatherN<2>(src, csr, ib0 + 2 * k, colb, a); k += 2; }
  if (k < P)      { gatherN<1>(src, csr, ib0 + 2 * k, colb, a); }
  if ((cnt & 1) && half == 0) {
    bf16x8 v = *(const bf16x8*)&src[(size_t)csr[e - 1] * HID_DIM + colb];
#pragma unroll
    for (int c = 0; c < 8; ++c) a[c] += bf2f((unsigned short)v[c]);
  }
#pragma unroll
  for (int c = 0; c < 8; ++c) a[c] += __shfl_xor(a[c], 32);
}

__global__ void k_agg1(const unsigned short* __restrict__ Cl,
                       const unsigned short* __restrict__ Cr,
                       const int* __restrict__ off, const int* __restrict__ csr,
                       unsigned short* __restrict__ h, int nNodes) {
  int node = blockIdx.x * 4 + (threadIdx.x >> 6);
  if (node >= nNodes) return;
  const int l = threadIdx.x & 63;
  const int half = l >> 5, li = l & 31;
  const size_t colb = (size_t)li * 8;
  int s = off[node], e = off[node + 1];
  float a[8] = {};
  agg_sum(Cl, csr, s, e, half, colb, a);
  if (half == 0) {
    float inv = 1.0f / fmaxf((float)(e - s), 1.0f);
    bf16x8 xr = *(const bf16x8*)&Cr[(size_t)node * HID_DIM + colb];   // includes b1
    bf16x8 o;
#pragma unroll
    for (int c = 0; c < 8; ++c)
      o[c] = (short)f2bf(fmaxf(a[c] * inv + bf2f((unsigned short)xr[c]), 0.0f));
    *(bf16x8*)&h[(size_t)node * HID_DIM + colb] = o;
  }
}

__global__ void k_agg2(const unsigned short* __restrict__ hsrc,
                       const int* __restrict__ off, const int* __restrict__ csr,
                       unsigned short* __restrict__ mean2, int nNodes) {
  int node = blockIdx.x * 4 + (threadIdx.x >> 6);
  if (node >= nNodes) return;
  const int l = threadIdx.x & 63;
  const int half = l >> 5, li = l & 31;
  const size_t colb = (size_t)li * 8;
  int s = off[node], e = off[node + 1];
  float a[8] = {};
  agg_sum(hsrc, csr, s, e, half, colb, a);
  if (half == 0) {
    float inv = 1.0f / fmaxf((float)(e - s), 1.0f);
    bf16x8 o;
#pragma unroll
    for (int c = 0; c < 8; ++c) o[c] = (short)f2bf(a[c] * inv);
    *(bf16x8*)&mean2[(size_t)node * HID_DIM + colb] = o;
  }
}

extern "C" void kernel_launch(void* const* d_in, const int* in_sizes, int n_in,
                              void* d_out, int out_size, void* d_ws, size_t ws_size,
                              hipStream_t stream) {
  const float* x   = (const float*)d_in[0];
  const void*  ei  = d_in[1];
  const float* w1l = (const float*)d_in[2];
  const float* w1r = (const float*)d_in[3];
  const float* b1  = (const float*)d_in[4];
  const float* w2l = (const float*)d_in[5];
  const float* w2r = (const float*)d_in[6];
  const float* b2  = (const float*)d_in[7];
  float* out = (float*)d_out;

  const int nN   = in_sizes[0] / IN_DIM;         // 50000
  const int nE   = in_sizes[1] / 2;              // 800000
  const int Mpad = (nN + 127) & ~127;            // 50048
  const int padN = (nN + 1023) & ~1023;          // 50176 (scan granularity)

  char* ws = (char*)d_ws;
  size_t o = 0;
  auto alloc = [&](size_t bytes) {
    char* p = ws + o;
    o += (bytes + 255) & ~(size_t)255;
    return p;
  };
  unsigned short* W1c   = (unsigned short*)alloc((size_t)2 * HID_DIM * IN_DIM * 2);
  unsigned short* W2c   = (unsigned short*)alloc((size_t)OUT_N * 2 * HID_DIM * 2);
  unsigned short* Cl    = (unsigned short*)alloc((size_t)Mpad * HID_DIM * 2);
  unsigned short* Cr    = (unsigned short*)alloc((size_t)Mpad * HID_DIM * 2);
  unsigned short* hbuf  = (unsigned short*)alloc((size_t)Mpad * HID_DIM * 2);
  unsigned short* mean2 = (unsigned short*)alloc((size_t)Mpad * HID_DIM * 2);
  int* deg    = (int*)alloc((size_t)padN * 4);         // zero-padded for int4 scan
  int* offs   = (int*)alloc((size_t)padN * 4);         // off[nN]=nE lands in pad region
  int* cursor = (int*)alloc((size_t)padN * 4);
  int* csr    = (int*)alloc((size_t)nE * 4);
  int* flag   = (int*)alloc(256);

  hipMemsetAsync(deg, 0, (size_t)padN * 4, stream);
  // pad rows of hbuf / mean2 stay 0xAA poison: decodes to ~1e-13 bf16, flows
  // only into pad rows of out-guarded stores -> never observed.  Cl/Cr pad
  // rows hold dup-of-last-row values (clamped A reads) -> never read (csr
  // indices < nN, agg node < nN).

  const int nEb   = (nE + 255) / 256;
  const int ngemm = 4 * (Mpad / 128);            // 1564

  k_pre<<<769 + nEb, 256, 0, stream>>>((const unsigned int*)ei, ei, flag,
                                       w1l, w1r, W1c, w2l, w2r, W2c, nE, deg);
  k_scan1<<<1, 1024, 0, stream>>>(deg, offs, cursor, padN / 4);
  k_g1f<<<ngemm + nEb, 256, 0, stream>>>(x, W1c, Cl, Cr, b1, nN - 1, ngemm,
                                         ei, nE, flag, cursor, csr);
  k_agg1<<<(nN + 3) / 4, 256, 0, stream>>>(Cl, Cr, offs, csr, hbuf, nN);
  k_agg2<<<(nN + 3) / 4, 256, 0, stream>>>(hbuf, offs, csr, mean2, nN);
  dim3 g2(512 / 128, Mpad / 128);
  k_gemm2<<<g2, 256, 0, stream>>>(mean2, hbuf, W2c, out, b2, nN);
}